// Round 3
// baseline (1095.195 us; speedup 1.0000x reference)
//
#include <hip/hip_runtime.h>
#include <math.h>

// Problem constants (from reference)
#define B_TOK 2048
#define SEQ   128
#define D_DIM 1024
#define E_NUM 16
#define H_DIM 2048

// GEMM tiling
#define TM 128          // rows (entries) per block
#define TN 64           // output cols per block
#define KT 32           // K per step (one MFMA K)
#define A_LD 40         // LDS row stride in shorts (80B: 2-way bank alias = free, 16B aligned)

typedef __attribute__((ext_vector_type(8))) short short8;   // bf16x8 MFMA operand
typedef __attribute__((ext_vector_type(4))) float f32x4;    // MFMA accumulator

__device__ __forceinline__ float bf2f(unsigned short h) {
  return __uint_as_float(((unsigned)h) << 16);
}

// truncation split: x ~= hi + lo, both bf16, |err| <= 2^-16 |x|
__device__ __forceinline__ void split2(float x, unsigned short& hi, unsigned short& lo) {
  unsigned u = __float_as_uint(x);
  hi = (unsigned short)(u >> 16);
  float lof = x - __uint_as_float(u & 0xFFFF0000u);
  lo = (unsigned short)(__float_as_uint(lof) >> 16);
}

// ---------------- embed mean-pool -> h split into (hi,lo) bf16 pairs --------
// 8-deep load batching: ~32 data VGPRs in flight per wave (was ~4) to cover
// the ~600cyc L3/HBM gather latency. (256,8): keep 8 waves/SIMD (VGPR<=64).
__global__ __launch_bounds__(256, 8) void k_embed_mean(const int* __restrict__ x,
                                                       const float* __restrict__ embed,
                                                       unsigned short* __restrict__ h_hi,
                                                       unsigned short* __restrict__ h_lo) {
  const int b = blockIdx.x;
  const int t = threadIdx.x;          // 256 threads, 4 floats each = 1024 = D
  __shared__ int sx[SEQ];
  if (t < SEQ) sx[t] = x[b * SEQ + t];
  __syncthreads();
  const int col = t * 4;
  float ax = 0.f, ay = 0.f, az = 0.f, aw = 0.f;
  for (int s0 = 0; s0 < SEQ; s0 += 8) {
    float4 v[8];
#pragma unroll
    for (int j = 0; j < 8; ++j) {
      v[j] = *reinterpret_cast<const float4*>(embed + (size_t)sx[s0 + j] * D_DIM + col);
    }
#pragma unroll
    for (int j = 0; j < 8; ++j) {
      ax += v[j].x; ay += v[j].y; az += v[j].z; aw += v[j].w;
    }
  }
  const float inv = 1.0f / (float)SEQ;
  float vv[4] = {ax * inv, ay * inv, az * inv, aw * inv};
  ushort4 hv, lv;
  split2(vv[0], hv.x, lv.x); split2(vv[1], hv.y, lv.y);
  split2(vv[2], hv.z, lv.z); split2(vv[3], hv.w, lv.w);
  *reinterpret_cast<ushort4*>(h_hi + (size_t)b * D_DIM + col) = hv;
  *reinterpret_cast<ushort4*>(h_lo + (size_t)b * D_DIM + col) = lv;
}

// ---------------- gate: softmax top-2, build expert lists -------------------
__global__ __launch_bounds__(64) void k_gate(const unsigned short* __restrict__ h_hi,
                                             const unsigned short* __restrict__ h_lo,
                                             const float* __restrict__ gate_w,
                                             const float* __restrict__ gate_b,
                                             int* __restrict__ counts,
                                             int* __restrict__ lists,
                                             float* __restrict__ wlist,
                                             float* __restrict__ out_idx) {
  const int b = blockIdx.x;
  const int l = threadIdx.x;          // one wave per token
  float z[E_NUM];
#pragma unroll
  for (int e = 0; e < E_NUM; ++e) z[e] = 0.f;
  const size_t base = (size_t)b * D_DIM;
  for (int d = l; d < D_DIM; d += 64) {
    const float hv = bf2f(h_hi[base + d]) + bf2f(h_lo[base + d]);
    const float* gw = gate_w + d * E_NUM;
#pragma unroll
    for (int e = 0; e < E_NUM; ++e) z[e] = fmaf(hv, gw[e], z[e]);
  }
#pragma unroll
  for (int e = 0; e < E_NUM; ++e) {
    float v = z[e];
#pragma unroll
    for (int off = 32; off >= 1; off >>= 1) v += __shfl_xor(v, off, 64);
    z[e] = v;
  }
  if (l == 0) {
#pragma unroll
    for (int e = 0; e < E_NUM; ++e) z[e] += gate_b[e];
    float mx = z[0];
#pragma unroll
    for (int e = 1; e < E_NUM; ++e) mx = fmaxf(mx, z[e]);
    float p[E_NUM];
    float se = 0.f;
#pragma unroll
    for (int e = 0; e < E_NUM; ++e) { p[e] = expf(z[e] - mx); se += p[e]; }
    const float invs = 1.0f / se;
    int e1 = 0; float z1 = z[0];
#pragma unroll
    for (int e = 1; e < E_NUM; ++e) if (z[e] > z1) { z1 = z[e]; e1 = e; }
    int e2 = -1; float z2 = -1e30f;
#pragma unroll
    for (int e = 0; e < E_NUM; ++e) if (e != e1 && z[e] > z2) { z2 = z[e]; e2 = e; }
    const float w1v = p[e1] * invs;
    const float w2v = p[e2] * invs;
    const int pos1 = atomicAdd(&counts[e1], 1);
    lists[e1 * B_TOK + pos1] = b * 2 + 0;   // entry id = b*2 + slot
    wlist[e1 * B_TOK + pos1] = w1v;
    const int pos2 = atomicAdd(&counts[e2], 1);
    lists[e2 * B_TOK + pos2] = b * 2 + 1;
    wlist[e2 * B_TOK + pos2] = w2v;
    out_idx[b * 2 + 0] = (float)e1;
    out_idx[b * 2 + 1] = (float)e2;
  }
}

// ---------------- expert layer 1 (MFMA, split-bf16): act = relu(h@w1+b1) ----
// Register-prefetch double buffer: tile k+1 global loads issue while MFMA
// runs on tile k, hiding global latency behind ~250cyc of matrix work.
__global__ __launch_bounds__(256) void k_gemm1(const unsigned short* __restrict__ a_hi,
                                               const unsigned short* __restrict__ a_lo,
                                               const float* __restrict__ w1,
                                               const float* __restrict__ b1,
                                               const int* __restrict__ counts,
                                               const int* __restrict__ lists,
                                               unsigned short* __restrict__ act_hi,
                                               unsigned short* __restrict__ act_lo) {
  const int e = blockIdx.z;
  const int n_e = counts[e];
  const int m0 = blockIdx.y * TM;
  if (m0 >= n_e) return;
  const int n0 = blockIdx.x * TN;
  const int* lst = lists + e * B_TOK;

  __shared__ short AsH[TM][A_LD];
  __shared__ short AsL[TM][A_LD];
  __shared__ short BsH[TN][A_LD];
  __shared__ short BsL[TN][A_LD];

  const int tid = threadIdx.x;
  // ---- A staging: thread -> (row r0 + 32*pass, slot sl) ----
  const int r0 = tid >> 3;
  const int sl = tid & 7;           // 0-3 hi quarters, 4-7 lo quarters
  const int spart = sl & 3;
  const unsigned short* abase = (sl < 4) ? a_hi : a_lo;
  short* lds_a = (sl < 4) ? &AsH[0][0] : &AsL[0][0];
  size_t arowoff[4];
#pragma unroll
  for (int p = 0; p < 4; ++p) {
    const int m = m0 + p * 32 + r0;
    const int ent = lst[(m < n_e) ? m : 0];
    arowoff[p] = (size_t)(ent >> 1) * D_DIM;   // token row in h
  }
  // ---- B staging: thread -> (col bn, k-quad bkq) ----
  const int bn = tid & 63;
  const int bkq = tid >> 6;
  const float* bcol = w1 + (size_t)e * D_DIM * H_DIM + n0 + bn;

  // ---- compute setup ----
  const int wv = tid >> 6;
  const int lane = tid & 63;
  const int fm = lane & 15;
  const int fq = lane >> 4;
  const int mrow = wv * 32;
  f32x4 acc[2][4];
#pragma unroll
  for (int mi = 0; mi < 2; ++mi)
#pragma unroll
    for (int ni = 0; ni < 4; ++ni) acc[mi][ni] = (f32x4){0.f, 0.f, 0.f, 0.f};

  // prologue: prefetch tile 0 into registers
  int4 pa[4];
  float pf[8];
#pragma unroll
  for (int p = 0; p < 4; ++p)
    pa[p] = *reinterpret_cast<const int4*>(abase + arowoff[p] + 8 * spart);
#pragma unroll
  for (int j = 0; j < 8; ++j)
    pf[j] = bcol[(size_t)(bkq * 8 + j) * H_DIM];

  for (int kb = 0; kb < D_DIM; kb += KT) {
    // write staged tile kb to LDS
#pragma unroll
    for (int p = 0; p < 4; ++p)
      *reinterpret_cast<int4*>(lds_a + (p * 32 + r0) * A_LD + 8 * spart) = pa[p];
    {
      unsigned u[8], lw[8];
#pragma unroll
      for (int j = 0; j < 8; ++j) {
        u[j] = __float_as_uint(pf[j]);
        lw[j] = __float_as_uint(pf[j] - __uint_as_float(u[j] & 0xFFFF0000u));
      }
      int4 hv, lv;
      hv.x = (int)((u[0] >> 16) | (u[1] & 0xFFFF0000u));
      hv.y = (int)((u[2] >> 16) | (u[3] & 0xFFFF0000u));
      hv.z = (int)((u[4] >> 16) | (u[5] & 0xFFFF0000u));
      hv.w = (int)((u[6] >> 16) | (u[7] & 0xFFFF0000u));
      lv.x = (int)((lw[0] >> 16) | (lw[1] & 0xFFFF0000u));
      lv.y = (int)((lw[2] >> 16) | (lw[3] & 0xFFFF0000u));
      lv.z = (int)((lw[4] >> 16) | (lw[5] & 0xFFFF0000u));
      lv.w = (int)((lw[6] >> 16) | (lw[7] & 0xFFFF0000u));
      *reinterpret_cast<int4*>(&BsH[bn][bkq * 8]) = hv;
      *reinterpret_cast<int4*>(&BsL[bn][bkq * 8]) = lv;
    }
    __syncthreads();
    // prefetch tile kb+KT while computing on kb
    if (kb + KT < D_DIM) {
#pragma unroll
      for (int p = 0; p < 4; ++p)
        pa[p] = *reinterpret_cast<const int4*>(abase + arowoff[p] + kb + KT + 8 * spart);
#pragma unroll
      for (int j = 0; j < 8; ++j)
        pf[j] = bcol[(size_t)(kb + KT + bkq * 8 + j) * H_DIM];
    }
    short8 aH[2], aL[2], bH[4], bL[4];
#pragma unroll
    for (int mi = 0; mi < 2; ++mi) {
      aH[mi] = *reinterpret_cast<const short8*>(&AsH[mrow + mi * 16 + fm][fq * 8]);
      aL[mi] = *reinterpret_cast<const short8*>(&AsL[mrow + mi * 16 + fm][fq * 8]);
    }
#pragma unroll
    for (int ni = 0; ni < 4; ++ni) {
      bH[ni] = *reinterpret_cast<const short8*>(&BsH[ni * 16 + fm][fq * 8]);
      bL[ni] = *reinterpret_cast<const short8*>(&BsL[ni * 16 + fm][fq * 8]);
    }
#pragma unroll
    for (int mi = 0; mi < 2; ++mi)
#pragma unroll
      for (int ni = 0; ni < 4; ++ni) {
        acc[mi][ni] = __builtin_amdgcn_mfma_f32_16x16x32_bf16(aH[mi], bH[ni], acc[mi][ni], 0, 0, 0);
        acc[mi][ni] = __builtin_amdgcn_mfma_f32_16x16x32_bf16(aH[mi], bL[ni], acc[mi][ni], 0, 0, 0);
        acc[mi][ni] = __builtin_amdgcn_mfma_f32_16x16x32_bf16(aL[mi], bH[ni], acc[mi][ni], 0, 0, 0);
      }
    __syncthreads();
  }
  // epilogue: +bias, relu, split to bf16 hi/lo
  float bz[4];
#pragma unroll
  for (int ni = 0; ni < 4; ++ni) bz[ni] = b1[(size_t)e * H_DIM + n0 + ni * 16 + fm];
#pragma unroll
  for (int mi = 0; mi < 2; ++mi) {
#pragma unroll
    for (int r = 0; r < 4; ++r) {
      const int m = m0 + mrow + mi * 16 + fq * 4 + r;
      if (m < n_e) {
        const int ent = lst[m];
        unsigned short* oh = act_hi + (size_t)ent * H_DIM + n0 + fm;
        unsigned short* ol = act_lo + (size_t)ent * H_DIM + n0 + fm;
#pragma unroll
        for (int ni = 0; ni < 4; ++ni) {
          float v = fmaxf(acc[mi][ni][r] + bz[ni], 0.f);
          unsigned short hh, ll;
          split2(v, hh, ll);
          oh[ni * 16] = hh;
          ol[ni * 16] = ll;
        }
      }
    }
  }
}

// ---- expert layer 2 (MFMA, split-bf16): combined += w*(act@w2+b2) ----------
// K-split by 2 (blockIdx.y parity): doubles active blocks (2->4 per CU);
// epilogue is atomicAdd so K-partials combine for free. Bias from kslice 0.
__global__ __launch_bounds__(256) void k_gemm2(const unsigned short* __restrict__ a_hi,
                                               const unsigned short* __restrict__ a_lo,
                                               const float* __restrict__ w2,
                                               const float* __restrict__ b2,
                                               const int* __restrict__ counts,
                                               const int* __restrict__ lists,
                                               const float* __restrict__ wlist,
                                               float* __restrict__ combined) {
  const int e = blockIdx.z;
  const int n_e = counts[e];
  const int kslice = blockIdx.y & 1;
  const int m0 = (blockIdx.y >> 1) * TM;
  if (m0 >= n_e) return;
  const int n0 = blockIdx.x * TN;
  const int* lst = lists + e * B_TOK;
  const int kbeg = kslice * (H_DIM / 2);
  const int kend = kbeg + (H_DIM / 2);

  __shared__ short AsH[TM][A_LD];
  __shared__ short AsL[TM][A_LD];
  __shared__ short BsH[TN][A_LD];
  __shared__ short BsL[TN][A_LD];

  const int tid = threadIdx.x;
  const int r0 = tid >> 3;
  const int sl = tid & 7;
  const int spart = sl & 3;
  const unsigned short* abase = (sl < 4) ? a_hi : a_lo;
  short* lds_a = (sl < 4) ? &AsH[0][0] : &AsL[0][0];
  size_t arowoff[4];
#pragma unroll
  for (int p = 0; p < 4; ++p) {
    const int m = m0 + p * 32 + r0;
    const int ent = lst[(m < n_e) ? m : 0];
    arowoff[p] = (size_t)ent * H_DIM;          // act row = entry
  }
  const int bn = tid & 63;
  const int bkq = tid >> 6;
  const float* bcol = w2 + (size_t)e * H_DIM * D_DIM + n0 + bn;

  const int wv = tid >> 6;
  const int lane = tid & 63;
  const int fm = lane & 15;
  const int fq = lane >> 4;
  const int mrow = wv * 32;
  f32x4 acc[2][4];
#pragma unroll
  for (int mi = 0; mi < 2; ++mi)
#pragma unroll
    for (int ni = 0; ni < 4; ++ni) acc[mi][ni] = (f32x4){0.f, 0.f, 0.f, 0.f};

  int4 pa[4];
  float pf[8];
#pragma unroll
  for (int p = 0; p < 4; ++p)
    pa[p] = *reinterpret_cast<const int4*>(abase + arowoff[p] + kbeg + 8 * spart);
#pragma unroll
  for (int j = 0; j < 8; ++j)
    pf[j] = bcol[(size_t)(kbeg + bkq * 8 + j) * D_DIM];

  for (int kb = kbeg; kb < kend; kb += KT) {
#pragma unroll
    for (int p = 0; p < 4; ++p)
      *reinterpret_cast<int4*>(lds_a + (p * 32 + r0) * A_LD + 8 * spart) = pa[p];
    {
      unsigned u[8], lw[8];
#pragma unroll
      for (int j = 0; j < 8; ++j) {
        u[j] = __float_as_uint(pf[j]);
        lw[j] = __float_as_uint(pf[j] - __uint_as_float(u[j] & 0xFFFF0000u));
      }
      int4 hv, lv;
      hv.x = (int)((u[0] >> 16) | (u[1] & 0xFFFF0000u));
      hv.y = (int)((u[2] >> 16) | (u[3] & 0xFFFF0000u));
      hv.z = (int)((u[4] >> 16) | (u[5] & 0xFFFF0000u));
      hv.w = (int)((u[6] >> 16) | (u[7] & 0xFFFF0000u));
      lv.x = (int)((lw[0] >> 16) | (lw[1] & 0xFFFF0000u));
      lv.y = (int)((lw[2] >> 16) | (lw[3] & 0xFFFF0000u));
      lv.z = (int)((lw[4] >> 16) | (lw[5] & 0xFFFF0000u));
      lv.w = (int)((lw[6] >> 16) | (lw[7] & 0xFFFF0000u));
      *reinterpret_cast<int4*>(&BsH[bn][bkq * 8]) = hv;
      *reinterpret_cast<int4*>(&BsL[bn][bkq * 8]) = lv;
    }
    __syncthreads();
    if (kb + KT < kend) {
#pragma unroll
      for (int p = 0; p < 4; ++p)
        pa[p] = *reinterpret_cast<const int4*>(abase + arowoff[p] + kb + KT + 8 * spart);
#pragma unroll
      for (int j = 0; j < 8; ++j)
        pf[j] = bcol[(size_t)(kb + KT + bkq * 8 + j) * D_DIM];
    }
    short8 aH[2], aL[2], bH[4], bL[4];
#pragma unroll
    for (int mi = 0; mi < 2; ++mi) {
      aH[mi] = *reinterpret_cast<const short8*>(&AsH[mrow + mi * 16 + fm][fq * 8]);
      aL[mi] = *reinterpret_cast<const short8*>(&AsL[mrow + mi * 16 + fm][fq * 8]);
    }
#pragma unroll
    for (int ni = 0; ni < 4; ++ni) {
      bH[ni] = *reinterpret_cast<const short8*>(&BsH[ni * 16 + fm][fq * 8]);
      bL[ni] = *reinterpret_cast<const short8*>(&BsL[ni * 16 + fm][fq * 8]);
    }
#pragma unroll
    for (int mi = 0; mi < 2; ++mi)
#pragma unroll
      for (int ni = 0; ni < 4; ++ni) {
        acc[mi][ni] = __builtin_amdgcn_mfma_f32_16x16x32_bf16(aH[mi], bH[ni], acc[mi][ni], 0, 0, 0);
        acc[mi][ni] = __builtin_amdgcn_mfma_f32_16x16x32_bf16(aH[mi], bL[ni], acc[mi][ni], 0, 0, 0);
        acc[mi][ni] = __builtin_amdgcn_mfma_f32_16x16x32_bf16(aL[mi], bH[ni], acc[mi][ni], 0, 0, 0);
      }
    __syncthreads();
  }
  float bz[4];
#pragma unroll
  for (int ni = 0; ni < 4; ++ni)
    bz[ni] = (kslice == 0) ? b2[(size_t)e * D_DIM + n0 + ni * 16 + fm] : 0.f;
#pragma unroll
  for (int mi = 0; mi < 2; ++mi) {
#pragma unroll
    for (int r = 0; r < 4; ++r) {
      const int m = m0 + mrow + mi * 16 + fq * 4 + r;
      if (m < n_e) {
        const int ent = lst[m];
        const float w = wlist[e * B_TOK + m];
        float* dst = combined + (size_t)(ent >> 1) * D_DIM + n0 + fm;
#pragma unroll
        for (int ni = 0; ni < 4; ++ni) {
          atomicAdd(&dst[ni * 16], w * (acc[mi][ni][r] + bz[ni]));
        }
      }
    }
  }
}

// ---------------- LayerNorm + head ------------------------------------------
__global__ __launch_bounds__(256) void k_ln_head(const float* __restrict__ combined,
                                                 const float* __restrict__ ln_g,
                                                 const float* __restrict__ ln_b,
                                                 const float* __restrict__ head_w,
                                                 const float* __restrict__ head_b,
                                                 float* __restrict__ logits) {
  const int b = blockIdx.x;
  const int t = threadIdx.x;
  const int lane = t & 63, wid = t >> 6;
  __shared__ float red[8];
  __shared__ float pr[4][20];
  const int d0 = t * 4;
  const float4 v = *reinterpret_cast<const float4*>(combined + (size_t)b * D_DIM + d0);
  float s = v.x + v.y + v.z + v.w;
#pragma unroll
  for (int off = 32; off >= 1; off >>= 1) s += __shfl_xor(s, off, 64);
  if (lane == 0) red[wid] = s;
  __syncthreads();
  const float mu = (red[0] + red[1] + red[2] + red[3]) * (1.0f / D_DIM);
  const float dx = v.x - mu, dy = v.y - mu, dz = v.z - mu, dw = v.w - mu;
  float sq = dx * dx + dy * dy + dz * dz + dw * dw;
#pragma unroll
  for (int off = 32; off >= 1; off >>= 1) sq += __shfl_xor(sq, off, 64);
  if (lane == 0) red[4 + wid] = sq;
  __syncthreads();
  const float var = (red[4] + red[5] + red[6] + red[7]) * (1.0f / D_DIM);
  const float inv = 1.0f / sqrtf(var + 1e-5f);
  float nm[4];
  nm[0] = dx * inv * ln_g[d0 + 0] + ln_b[d0 + 0];
  nm[1] = dy * inv * ln_g[d0 + 1] + ln_b[d0 + 1];
  nm[2] = dz * inv * ln_g[d0 + 2] + ln_b[d0 + 2];
  nm[3] = dw * inv * ln_g[d0 + 3] + ln_b[d0 + 3];
  float p[20];
#pragma unroll
  for (int j = 0; j < 20; ++j) p[j] = 0.f;
#pragma unroll
  for (int i = 0; i < 4; ++i) {
    const float* hwrow = head_w + (size_t)(d0 + i) * 20;
#pragma unroll
    for (int j = 0; j < 20; ++j) p[j] = fmaf(nm[i], hwrow[j], p[j]);
  }
#pragma unroll
  for (int j = 0; j < 20; ++j) {
    float pv = p[j];
#pragma unroll
    for (int off = 32; off >= 1; off >>= 1) pv += __shfl_xor(pv, off, 64);
    if (lane == 0) pr[wid][j] = pv;
  }
  __syncthreads();
  if (t < 20) {
    logits[(size_t)b * 20 + t] = pr[0][t] + pr[1][t] + pr[2][t] + pr[3][t] + head_b[t];
  }
}

extern "C" void kernel_launch(void* const* d_in, const int* in_sizes, int n_in,
                              void* d_out, int out_size, void* d_ws, size_t ws_size,
                              hipStream_t stream) {
  const int*   x      = (const int*)d_in[0];
  const float* embed  = (const float*)d_in[1];
  const float* gate_w = (const float*)d_in[2];
  const float* gate_b = (const float*)d_in[3];
  const float* w1     = (const float*)d_in[4];
  const float* b1     = (const float*)d_in[5];
  const float* w2     = (const float*)d_in[6];
  const float* b2     = (const float*)d_in[7];
  const float* ln_g   = (const float*)d_in[8];
  const float* ln_b   = (const float*)d_in[9];
  const float* head_w = (const float*)d_in[10];
  const float* head_b = (const float*)d_in[11];

  float* logits  = (float*)d_out;                  // [B,20] fp32
  float* out_idx = logits + (size_t)B_TOK * 20;    // [B,2] written as float

  char* ws = (char*)d_ws;
  size_t off = 0;
  auto alloc = [&](size_t bytes) -> void* {
    void* p = ws + off;
    off = (off + bytes + 255) & ~(size_t)255;
    return p;
  };
  unsigned short* h_hi   = (unsigned short*)alloc(sizeof(short) * B_TOK * D_DIM);      // 4 MB
  unsigned short* h_lo   = (unsigned short*)alloc(sizeof(short) * B_TOK * D_DIM);      // 4 MB
  float* combined        = (float*)alloc(sizeof(float) * B_TOK * D_DIM);               // 8 MB
  int*   counts          = (int*)alloc(sizeof(int) * E_NUM);
  int*   lists           = (int*)alloc(sizeof(int) * E_NUM * B_TOK);                   // 128 KB
  float* wlist           = (float*)alloc(sizeof(float) * E_NUM * B_TOK);               // 128 KB
  unsigned short* act_hi = (unsigned short*)alloc(sizeof(short) * B_TOK * 2 * H_DIM);  // 16 MB
  unsigned short* act_lo = (unsigned short*)alloc(sizeof(short) * B_TOK * 2 * H_DIM);  // 16 MB
  // total ~48.3 MB

  hipMemsetAsync(counts, 0, sizeof(int) * E_NUM, stream);
  hipMemsetAsync(combined, 0, sizeof(float) * B_TOK * D_DIM, stream);

  k_embed_mean<<<B_TOK, 256, 0, stream>>>(x, embed, h_hi, h_lo);
  k_gate<<<B_TOK, 64, 0, stream>>>(h_hi, h_lo, gate_w, gate_b, counts, lists, wlist, out_idx);
  k_gemm1<<<dim3(H_DIM / TN, B_TOK / TM, E_NUM), 256, 0, stream>>>(h_hi, h_lo, w1, b1, counts, lists, act_hi, act_lo);
  k_gemm2<<<dim3(D_DIM / TN, (B_TOK / TM) * 2, E_NUM), 256, 0, stream>>>(act_hi, act_lo, w2, b2, counts, lists, wlist, combined);
  k_ln_head<<<B_TOK, 256, 0, stream>>>(combined, ln_g, ln_b, head_w, head_b, logits);
}

// Round 4
// 752.165 us; speedup vs baseline: 1.4561x; 1.4561x over previous
//
#include <hip/hip_runtime.h>
#include <math.h>

// Problem constants (from reference)
#define B_TOK 2048
#define SEQ   128
#define D_DIM 1024
#define E_NUM 16
#define H_DIM 2048
#define N_ENT (B_TOK * 2)   // total routed entries (each token -> exactly 2 experts)

// GEMM tiling
#define TM 128          // rows (entries) per block
#define TN 64           // output cols per block
#define KT 32           // K per step (one MFMA K)
#define A_LD 40         // LDS row stride in shorts (80B: 2-way bank alias = free, 16B aligned)

typedef __attribute__((ext_vector_type(8))) short short8;   // bf16x8 MFMA operand
typedef __attribute__((ext_vector_type(4))) float f32x4;    // MFMA accumulator

__device__ __forceinline__ float bf2f(unsigned short h) {
  return __uint_as_float(((unsigned)h) << 16);
}

// truncation split: x ~= hi + lo, both bf16, |err| <= 2^-16 |x|
__device__ __forceinline__ void split2(float x, unsigned short& hi, unsigned short& lo) {
  unsigned u = __float_as_uint(x);
  hi = (unsigned short)(u >> 16);
  float lof = x - __uint_as_float(u & 0xFFFF0000u);
  lo = (unsigned short)(__float_as_uint(lof) >> 16);
}

// ---------------- embed mean-pool -> h split into (hi,lo) bf16 pairs --------
// 8-deep load batching to cover L3/HBM gather latency; (256,4) avoids any
// VGPR-cap spill risk while keeping 16 waves/CU x 8 outstanding loads.
__global__ __launch_bounds__(256, 4) void k_embed_mean(const int* __restrict__ x,
                                                       const float* __restrict__ embed,
                                                       unsigned short* __restrict__ h_hi,
                                                       unsigned short* __restrict__ h_lo) {
  const int b = blockIdx.x;
  const int t = threadIdx.x;          // 256 threads, 4 floats each = 1024 = D
  __shared__ int sx[SEQ];
  if (t < SEQ) sx[t] = x[b * SEQ + t];
  __syncthreads();
  const int col = t * 4;
  float ax = 0.f, ay = 0.f, az = 0.f, aw = 0.f;
  for (int s0 = 0; s0 < SEQ; s0 += 8) {
    float4 v[8];
#pragma unroll
    for (int j = 0; j < 8; ++j) {
      v[j] = *reinterpret_cast<const float4*>(embed + (size_t)sx[s0 + j] * D_DIM + col);
    }
#pragma unroll
    for (int j = 0; j < 8; ++j) {
      ax += v[j].x; ay += v[j].y; az += v[j].z; aw += v[j].w;
    }
  }
  const float inv = 1.0f / (float)SEQ;
  float vv[4] = {ax * inv, ay * inv, az * inv, aw * inv};
  ushort4 hv, lv;
  split2(vv[0], hv.x, lv.x); split2(vv[1], hv.y, lv.y);
  split2(vv[2], hv.z, lv.z); split2(vv[3], hv.w, lv.w);
  *reinterpret_cast<ushort4*>(h_hi + (size_t)b * D_DIM + col) = hv;
  *reinterpret_cast<ushort4*>(h_lo + (size_t)b * D_DIM + col) = lv;
}

// ---------------- gate: softmax top-2, build expert lists + per-entry weight -
__global__ __launch_bounds__(64) void k_gate(const unsigned short* __restrict__ h_hi,
                                             const unsigned short* __restrict__ h_lo,
                                             const float* __restrict__ gate_w,
                                             const float* __restrict__ gate_b,
                                             int* __restrict__ counts,
                                             int* __restrict__ lists,
                                             float* __restrict__ ew,
                                             float* __restrict__ out_idx) {
  const int b = blockIdx.x;
  const int l = threadIdx.x;          // one wave per token
  float z[E_NUM];
#pragma unroll
  for (int e = 0; e < E_NUM; ++e) z[e] = 0.f;
  const size_t base = (size_t)b * D_DIM;
  for (int d = l; d < D_DIM; d += 64) {
    const float hv = bf2f(h_hi[base + d]) + bf2f(h_lo[base + d]);
    const float* gw = gate_w + d * E_NUM;
#pragma unroll
    for (int e = 0; e < E_NUM; ++e) z[e] = fmaf(hv, gw[e], z[e]);
  }
#pragma unroll
  for (int e = 0; e < E_NUM; ++e) {
    float v = z[e];
#pragma unroll
    for (int off = 32; off >= 1; off >>= 1) v += __shfl_xor(v, off, 64);
    z[e] = v;
  }
  if (l == 0) {
#pragma unroll
    for (int e = 0; e < E_NUM; ++e) z[e] += gate_b[e];
    float mx = z[0];
#pragma unroll
    for (int e = 1; e < E_NUM; ++e) mx = fmaxf(mx, z[e]);
    float p[E_NUM];
    float se = 0.f;
#pragma unroll
    for (int e = 0; e < E_NUM; ++e) { p[e] = expf(z[e] - mx); se += p[e]; }
    const float invs = 1.0f / se;
    // top-2 on z (softmax monotonic); strict > == first-index tie-break (lax.top_k)
    int e1 = 0; float z1 = z[0];
#pragma unroll
    for (int e = 1; e < E_NUM; ++e) if (z[e] > z1) { z1 = z[e]; e1 = e; }
    int e2 = -1; float z2 = -1e30f;
#pragma unroll
    for (int e = 0; e < E_NUM; ++e) if (e != e1 && z[e] > z2) { z2 = z[e]; e2 = e; }
    const float w1v = p[e1] * invs;
    const float w2v = p[e2] * invs;
    const int pos1 = atomicAdd(&counts[e1], 1);
    lists[e1 * B_TOK + pos1] = b * 2 + 0;   // entry id = b*2 + slot
    const int pos2 = atomicAdd(&counts[e2], 1);
    lists[e2 * B_TOK + pos2] = b * 2 + 1;
    ew[b * 2 + 0] = w1v;                    // per-entry combine weight (gathered in ln_head)
    ew[b * 2 + 1] = w2v;
    out_idx[b * 2 + 0] = (float)e1;
    out_idx[b * 2 + 1] = (float)e2;
  }
}

// ---------------- expert layer 1 (MFMA, split-bf16): act = relu(h@w1+b1) ----
__global__ __launch_bounds__(256) void k_gemm1(const unsigned short* __restrict__ a_hi,
                                               const unsigned short* __restrict__ a_lo,
                                               const float* __restrict__ w1,
                                               const float* __restrict__ b1,
                                               const int* __restrict__ counts,
                                               const int* __restrict__ lists,
                                               unsigned short* __restrict__ act_hi,
                                               unsigned short* __restrict__ act_lo) {
  const int e = blockIdx.z;
  const int n_e = counts[e];
  const int m0 = blockIdx.y * TM;
  if (m0 >= n_e) return;
  const int n0 = blockIdx.x * TN;
  const int* lst = lists + e * B_TOK;

  __shared__ short AsH[TM][A_LD];
  __shared__ short AsL[TM][A_LD];
  __shared__ short BsH[TN][A_LD];
  __shared__ short BsL[TN][A_LD];

  const int tid = threadIdx.x;
  // ---- A staging: thread -> (row r0 + 32*pass, slot sl) ----
  const int r0 = tid >> 3;
  const int sl = tid & 7;           // 0-3 hi quarters, 4-7 lo quarters
  const int spart = sl & 3;
  const unsigned short* abase = (sl < 4) ? a_hi : a_lo;
  short* lds_a = (sl < 4) ? &AsH[0][0] : &AsL[0][0];
  size_t arowoff[4];
#pragma unroll
  for (int p = 0; p < 4; ++p) {
    const int m = m0 + p * 32 + r0;
    const int ent = lst[(m < n_e) ? m : 0];
    arowoff[p] = (size_t)(ent >> 1) * D_DIM;   // token row in h
  }
  // ---- B staging: thread -> (col bn, k-quad bkq) ----
  const int bn = tid & 63;
  const int bkq = tid >> 6;
  const float* bcol = w1 + (size_t)e * D_DIM * H_DIM + n0 + bn;

  // ---- compute setup ----
  const int wv = tid >> 6;
  const int lane = tid & 63;
  const int fm = lane & 15;
  const int fq = lane >> 4;
  const int mrow = wv * 32;
  f32x4 acc[2][4];
#pragma unroll
  for (int mi = 0; mi < 2; ++mi)
#pragma unroll
    for (int ni = 0; ni < 4; ++ni) acc[mi][ni] = (f32x4){0.f, 0.f, 0.f, 0.f};

  for (int kb = 0; kb < D_DIM; kb += KT) {
    // stage A (pure copy of pre-split bf16)
#pragma unroll
    for (int p = 0; p < 4; ++p) {
      const int4 v = *reinterpret_cast<const int4*>(abase + arowoff[p] + kb + 8 * spart);
      *reinterpret_cast<int4*>(lds_a + (p * 32 + r0) * A_LD + 8 * spart) = v;
    }
    // stage B (load fp32 weights, truncation-split to hi/lo bf16, store [n][k])
    {
      unsigned u[8], lw[8];
      float f[8];
#pragma unroll
      for (int j = 0; j < 8; ++j) {
        f[j] = bcol[(size_t)(kb + bkq * 8 + j) * H_DIM];
        u[j] = __float_as_uint(f[j]);
        lw[j] = __float_as_uint(f[j] - __uint_as_float(u[j] & 0xFFFF0000u));
      }
      int4 hv, lv;
      hv.x = (int)((u[0] >> 16) | (u[1] & 0xFFFF0000u));
      hv.y = (int)((u[2] >> 16) | (u[3] & 0xFFFF0000u));
      hv.z = (int)((u[4] >> 16) | (u[5] & 0xFFFF0000u));
      hv.w = (int)((u[6] >> 16) | (u[7] & 0xFFFF0000u));
      lv.x = (int)((lw[0] >> 16) | (lw[1] & 0xFFFF0000u));
      lv.y = (int)((lw[2] >> 16) | (lw[3] & 0xFFFF0000u));
      lv.z = (int)((lw[4] >> 16) | (lw[5] & 0xFFFF0000u));
      lv.w = (int)((lw[6] >> 16) | (lw[7] & 0xFFFF0000u));
      *reinterpret_cast<int4*>(&BsH[bn][bkq * 8]) = hv;
      *reinterpret_cast<int4*>(&BsL[bn][bkq * 8]) = lv;
    }
    __syncthreads();
    short8 aH[2], aL[2], bH[4], bL[4];
#pragma unroll
    for (int mi = 0; mi < 2; ++mi) {
      aH[mi] = *reinterpret_cast<const short8*>(&AsH[mrow + mi * 16 + fm][fq * 8]);
      aL[mi] = *reinterpret_cast<const short8*>(&AsL[mrow + mi * 16 + fm][fq * 8]);
    }
#pragma unroll
    for (int ni = 0; ni < 4; ++ni) {
      bH[ni] = *reinterpret_cast<const short8*>(&BsH[ni * 16 + fm][fq * 8]);
      bL[ni] = *reinterpret_cast<const short8*>(&BsL[ni * 16 + fm][fq * 8]);
    }
#pragma unroll
    for (int mi = 0; mi < 2; ++mi)
#pragma unroll
      for (int ni = 0; ni < 4; ++ni) {
        acc[mi][ni] = __builtin_amdgcn_mfma_f32_16x16x32_bf16(aH[mi], bH[ni], acc[mi][ni], 0, 0, 0);
        acc[mi][ni] = __builtin_amdgcn_mfma_f32_16x16x32_bf16(aH[mi], bL[ni], acc[mi][ni], 0, 0, 0);
        acc[mi][ni] = __builtin_amdgcn_mfma_f32_16x16x32_bf16(aL[mi], bH[ni], acc[mi][ni], 0, 0, 0);
      }
    __syncthreads();
  }
  // epilogue: +bias, relu, split to bf16 hi/lo
  float bz[4];
#pragma unroll
  for (int ni = 0; ni < 4; ++ni) bz[ni] = b1[(size_t)e * H_DIM + n0 + ni * 16 + fm];
#pragma unroll
  for (int mi = 0; mi < 2; ++mi) {
#pragma unroll
    for (int r = 0; r < 4; ++r) {
      const int m = m0 + mrow + mi * 16 + fq * 4 + r;
      if (m < n_e) {
        const int ent = lst[m];
        unsigned short* oh = act_hi + (size_t)ent * H_DIM + n0 + fm;
        unsigned short* ol = act_lo + (size_t)ent * H_DIM + n0 + fm;
#pragma unroll
        for (int ni = 0; ni < 4; ++ni) {
          float v = fmaxf(acc[mi][ni][r] + bz[ni], 0.f);
          unsigned short hh, ll;
          split2(v, hh, ll);
          oh[ni * 16] = hh;
          ol[ni * 16] = ll;
        }
      }
    }
  }
}

// ---- expert layer 2 (MFMA, split-bf16): y[ent] = act[ent]@w2[e] + b2[e] ----
// NO atomics: plain per-entry stores; combine happens as a gather in ln_head.
__global__ __launch_bounds__(256) void k_gemm2(const unsigned short* __restrict__ a_hi,
                                               const unsigned short* __restrict__ a_lo,
                                               const float* __restrict__ w2,
                                               const float* __restrict__ b2,
                                               const int* __restrict__ counts,
                                               const int* __restrict__ lists,
                                               float* __restrict__ y) {
  const int e = blockIdx.z;
  const int n_e = counts[e];
  const int m0 = blockIdx.y * TM;
  if (m0 >= n_e) return;
  const int n0 = blockIdx.x * TN;
  const int* lst = lists + e * B_TOK;

  __shared__ short AsH[TM][A_LD];
  __shared__ short AsL[TM][A_LD];
  __shared__ short BsH[TN][A_LD];
  __shared__ short BsL[TN][A_LD];

  const int tid = threadIdx.x;
  const int r0 = tid >> 3;
  const int sl = tid & 7;
  const int spart = sl & 3;
  const unsigned short* abase = (sl < 4) ? a_hi : a_lo;
  short* lds_a = (sl < 4) ? &AsH[0][0] : &AsL[0][0];
  size_t arowoff[4];
#pragma unroll
  for (int p = 0; p < 4; ++p) {
    const int m = m0 + p * 32 + r0;
    const int ent = lst[(m < n_e) ? m : 0];
    arowoff[p] = (size_t)ent * H_DIM;          // act row = entry
  }
  const int bn = tid & 63;
  const int bkq = tid >> 6;
  const float* bcol = w2 + (size_t)e * H_DIM * D_DIM + n0 + bn;

  const int wv = tid >> 6;
  const int lane = tid & 63;
  const int fm = lane & 15;
  const int fq = lane >> 4;
  const int mrow = wv * 32;
  f32x4 acc[2][4];
#pragma unroll
  for (int mi = 0; mi < 2; ++mi)
#pragma unroll
    for (int ni = 0; ni < 4; ++ni) acc[mi][ni] = (f32x4){0.f, 0.f, 0.f, 0.f};

  for (int kb = 0; kb < H_DIM; kb += KT) {
#pragma unroll
    for (int p = 0; p < 4; ++p) {
      const int4 v = *reinterpret_cast<const int4*>(abase + arowoff[p] + kb + 8 * spart);
      *reinterpret_cast<int4*>(lds_a + (p * 32 + r0) * A_LD + 8 * spart) = v;
    }
    {
      unsigned u[8], lw[8];
      float f[8];
#pragma unroll
      for (int j = 0; j < 8; ++j) {
        f[j] = bcol[(size_t)(kb + bkq * 8 + j) * D_DIM];
        u[j] = __float_as_uint(f[j]);
        lw[j] = __float_as_uint(f[j] - __uint_as_float(u[j] & 0xFFFF0000u));
      }
      int4 hv, lv;
      hv.x = (int)((u[0] >> 16) | (u[1] & 0xFFFF0000u));
      hv.y = (int)((u[2] >> 16) | (u[3] & 0xFFFF0000u));
      hv.z = (int)((u[4] >> 16) | (u[5] & 0xFFFF0000u));
      hv.w = (int)((u[6] >> 16) | (u[7] & 0xFFFF0000u));
      lv.x = (int)((lw[0] >> 16) | (lw[1] & 0xFFFF0000u));
      lv.y = (int)((lw[2] >> 16) | (lw[3] & 0xFFFF0000u));
      lv.z = (int)((lw[4] >> 16) | (lw[5] & 0xFFFF0000u));
      lv.w = (int)((lw[6] >> 16) | (lw[7] & 0xFFFF0000u));
      *reinterpret_cast<int4*>(&BsH[bn][bkq * 8]) = hv;
      *reinterpret_cast<int4*>(&BsL[bn][bkq * 8]) = lv;
    }
    __syncthreads();
    short8 aH[2], aL[2], bH[4], bL[4];
#pragma unroll
    for (int mi = 0; mi < 2; ++mi) {
      aH[mi] = *reinterpret_cast<const short8*>(&AsH[mrow + mi * 16 + fm][fq * 8]);
      aL[mi] = *reinterpret_cast<const short8*>(&AsL[mrow + mi * 16 + fm][fq * 8]);
    }
#pragma unroll
    for (int ni = 0; ni < 4; ++ni) {
      bH[ni] = *reinterpret_cast<const short8*>(&BsH[ni * 16 + fm][fq * 8]);
      bL[ni] = *reinterpret_cast<const short8*>(&BsL[ni * 16 + fm][fq * 8]);
    }
#pragma unroll
    for (int mi = 0; mi < 2; ++mi)
#pragma unroll
      for (int ni = 0; ni < 4; ++ni) {
        acc[mi][ni] = __builtin_amdgcn_mfma_f32_16x16x32_bf16(aH[mi], bH[ni], acc[mi][ni], 0, 0, 0);
        acc[mi][ni] = __builtin_amdgcn_mfma_f32_16x16x32_bf16(aH[mi], bL[ni], acc[mi][ni], 0, 0, 0);
        acc[mi][ni] = __builtin_amdgcn_mfma_f32_16x16x32_bf16(aL[mi], bH[ni], acc[mi][ni], 0, 0, 0);
      }
    __syncthreads();
  }
  float bz[4];
#pragma unroll
  for (int ni = 0; ni < 4; ++ni) bz[ni] = b2[(size_t)e * D_DIM + n0 + ni * 16 + fm];
#pragma unroll
  for (int mi = 0; mi < 2; ++mi) {
#pragma unroll
    for (int r = 0; r < 4; ++r) {
      const int m = m0 + mrow + mi * 16 + fq * 4 + r;
      if (m < n_e) {
        const int ent = lst[m];
        float* dst = y + (size_t)ent * D_DIM + n0 + fm;
#pragma unroll
        for (int ni = 0; ni < 4; ++ni) {
          dst[ni * 16] = acc[mi][ni][r] + bz[ni];   // plain store, no RMW
        }
      }
    }
  }
}

// ---------------- combine (gather) + LayerNorm + head -----------------------
__global__ __launch_bounds__(256) void k_ln_head(const float* __restrict__ y,
                                                 const float* __restrict__ ew,
                                                 const float* __restrict__ ln_g,
                                                 const float* __restrict__ ln_b,
                                                 const float* __restrict__ head_w,
                                                 const float* __restrict__ head_b,
                                                 float* __restrict__ logits) {
  const int b = blockIdx.x;
  const int t = threadIdx.x;
  const int lane = t & 63, wid = t >> 6;
  __shared__ float red[8];
  __shared__ float pr[4][20];
  const int d0 = t * 4;
  const float w0 = ew[b * 2 + 0];
  const float w1 = ew[b * 2 + 1];
  const float4 va = *reinterpret_cast<const float4*>(y + (size_t)(b * 2 + 0) * D_DIM + d0);
  const float4 vb = *reinterpret_cast<const float4*>(y + (size_t)(b * 2 + 1) * D_DIM + d0);
  float4 v;
  v.x = w0 * va.x + w1 * vb.x;
  v.y = w0 * va.y + w1 * vb.y;
  v.z = w0 * va.z + w1 * vb.z;
  v.w = w0 * va.w + w1 * vb.w;
  float s = v.x + v.y + v.z + v.w;
#pragma unroll
  for (int off = 32; off >= 1; off >>= 1) s += __shfl_xor(s, off, 64);
  if (lane == 0) red[wid] = s;
  __syncthreads();
  const float mu = (red[0] + red[1] + red[2] + red[3]) * (1.0f / D_DIM);
  const float dx = v.x - mu, dy = v.y - mu, dz = v.z - mu, dw = v.w - mu;
  float sq = dx * dx + dy * dy + dz * dz + dw * dw;
#pragma unroll
  for (int off = 32; off >= 1; off >>= 1) sq += __shfl_xor(sq, off, 64);
  if (lane == 0) red[4 + wid] = sq;
  __syncthreads();
  const float var = (red[4] + red[5] + red[6] + red[7]) * (1.0f / D_DIM);
  const float inv = 1.0f / sqrtf(var + 1e-5f);
  float nm[4];
  nm[0] = dx * inv * ln_g[d0 + 0] + ln_b[d0 + 0];
  nm[1] = dy * inv * ln_g[d0 + 1] + ln_b[d0 + 1];
  nm[2] = dz * inv * ln_g[d0 + 2] + ln_b[d0 + 2];
  nm[3] = dw * inv * ln_g[d0 + 3] + ln_b[d0 + 3];
  float p[20];
#pragma unroll
  for (int j = 0; j < 20; ++j) p[j] = 0.f;
#pragma unroll
  for (int i = 0; i < 4; ++i) {
    const float* hwrow = head_w + (size_t)(d0 + i) * 20;
#pragma unroll
    for (int j = 0; j < 20; ++j) p[j] = fmaf(nm[i], hwrow[j], p[j]);
  }
#pragma unroll
  for (int j = 0; j < 20; ++j) {
    float pv = p[j];
#pragma unroll
    for (int off = 32; off >= 1; off >>= 1) pv += __shfl_xor(pv, off, 64);
    if (lane == 0) pr[wid][j] = pv;
  }
  __syncthreads();
  if (t < 20) {
    logits[(size_t)b * 20 + t] = pr[0][t] + pr[1][t] + pr[2][t] + pr[3][t] + head_b[t];
  }
}

extern "C" void kernel_launch(void* const* d_in, const int* in_sizes, int n_in,
                              void* d_out, int out_size, void* d_ws, size_t ws_size,
                              hipStream_t stream) {
  const int*   x      = (const int*)d_in[0];
  const float* embed  = (const float*)d_in[1];
  const float* gate_w = (const float*)d_in[2];
  const float* gate_b = (const float*)d_in[3];
  const float* w1     = (const float*)d_in[4];
  const float* b1     = (const float*)d_in[5];
  const float* w2     = (const float*)d_in[6];
  const float* b2     = (const float*)d_in[7];
  const float* ln_g   = (const float*)d_in[8];
  const float* ln_b   = (const float*)d_in[9];
  const float* head_w = (const float*)d_in[10];
  const float* head_b = (const float*)d_in[11];

  float* logits  = (float*)d_out;                  // [B,20] fp32
  float* out_idx = logits + (size_t)B_TOK * 20;    // [B,2] written as float

  // Workspace layout (stream-serial kernels let y alias the dead h buffers):
  //   [0          .. 16.78M) : y [N_ENT][D] fp32   (written by gemm2)
  //     aliases h_hi [0..4.19M) + h_lo [4.19M..8.39M)  (dead after gemm1)
  //   [16.78M .. 33.55M) : act_hi bf16 [N_ENT][H]
  //   [33.55M .. 50.33M) : act_lo bf16 [N_ENT][H]
  //   [50.33M .. +~150K) : counts, lists, ew
  char* ws = (char*)d_ws;
  const size_t Y_BYTES = sizeof(float) * (size_t)N_ENT * D_DIM;            // 16.78 MB
  const size_t ACT_BYTES = sizeof(short) * (size_t)N_ENT * H_DIM;          // 16.78 MB
  unsigned short* h_hi   = (unsigned short*)(ws + 0);
  unsigned short* h_lo   = (unsigned short*)(ws + sizeof(short) * (size_t)B_TOK * D_DIM);
  float*          y      = (float*)(ws + 0);                               // alias over h
  unsigned short* act_hi = (unsigned short*)(ws + Y_BYTES);
  unsigned short* act_lo = (unsigned short*)(ws + Y_BYTES + ACT_BYTES);
  char* tail = ws + Y_BYTES + 2 * ACT_BYTES;
  int*   counts = (int*)tail;                       tail += 256;
  int*   lists  = (int*)tail;                       tail += sizeof(int) * E_NUM * B_TOK;
  float* ew     = (float*)tail;                     // [N_ENT]
  // total ~50.48 MB (< 50.59 MB proven in round 1)

  hipMemsetAsync(counts, 0, sizeof(int) * E_NUM, stream);

  k_embed_mean<<<B_TOK, 256, 0, stream>>>(x, embed, h_hi, h_lo);
  k_gate<<<B_TOK, 64, 0, stream>>>(h_hi, h_lo, gate_w, gate_b, counts, lists, ew, out_idx);
  k_gemm1<<<dim3(H_DIM / TN, B_TOK / TM, E_NUM), 256, 0, stream>>>(h_hi, h_lo, w1, b1, counts, lists, act_hi, act_lo);
  k_gemm2<<<dim3(D_DIM / TN, B_TOK / TM, E_NUM), 256, 0, stream>>>(act_hi, act_lo, w2, b2, counts, lists, y);
  k_ln_head<<<B_TOK, 256, 0, stream>>>(y, ew, ln_g, ln_b, head_w, head_b, logits);
}